// Round 1
// baseline (150.355 us; speedup 1.0000x reference)
//
#include <hip/hip_runtime.h>
#include <hip/hip_bf16.h>

#define NQ   8
#define HID  768
#define BATCH 8192
#define SPB  16                      // samples per block
#define NBLK (BATCH / SPB)           // 512
#define TPB  256

// ---------- dtype-generic load/store ----------
template<int BF> __device__ __forceinline__ float LDV(const void* p, int i) {
    if constexpr (BF) return __bfloat162float(((const __hip_bfloat16*)p)[i]);
    else return ((const float*)p)[i];
}
template<int BF> __device__ __forceinline__ void STV(void* p, int i, float v) {
    if constexpr (BF) ((__hip_bfloat16*)p)[i] = __float2bfloat16(v);
    else ((float*)p)[i] = v;
}

// ws layout: int flag at byte 0; float qc[32] at byte 16 (DA,DB,Kre,Kim per qubit)

// ---------- setup: dtype sniff + per-qubit circuit constants ----------
__global__ void setup_kernel(const void* hidden, const void* wry, const void* wrz, void* ws) {
    __shared__ int votes;
    __shared__ int sFlag;
    int tid = threadIdx.x;
    if (tid == 0) votes = 0;
    __syncthreads();
    // bf16-likeness of low 16 bits of first 4096 words of `hidden`
    const unsigned int* hw = (const unsigned int*)hidden;
    int cnt = 0;
    #pragma unroll
    for (int k = 0; k < 16; ++k) {
        unsigned int w = hw[tid * 16 + k];
        unsigned int lo = w & 0xffffu;
        unsigned int e = (lo >> 7) & 0xffu;
        if (lo == 0u || (e >= 100u && e <= 133u)) cnt++;
    }
    atomicAdd(&votes, cnt);
    __syncthreads();
    if (tid == 0) {
        sFlag = (votes * 2 > TPB * 16) ? 1 : 0;
        *(int*)ws = sFlag;
    }
    __syncthreads();
    const int flag = sFlag;
    if (tid < NQ) {
        float ry0, ry1, rz0, rz1;
        if (flag) {
            ry0 = LDV<1>(wry, tid);  ry1 = LDV<1>(wry, NQ + tid);
            rz0 = LDV<1>(wrz, tid);  rz1 = LDV<1>(wrz, NQ + tid);
        } else {
            ry0 = LDV<0>(wry, tid);  ry1 = LDV<0>(wry, NQ + tid);
            rz0 = LDV<0>(wrz, tid);  rz1 = LDV<0>(wrz, NQ + tid);
        }
        float cA = cosf(0.5f*ry0), sA = sinf(0.5f*ry0);
        float cB = cosf(0.5f*ry1), sB = sinf(0.5f*ry1);
        float p0c = cosf(0.5f*rz0), p0s = sinf(0.5f*rz0);
        float p1c = cosf(0.5f*rz1), p1s = sinf(0.5f*rz1);
        // G1 = RZ0 * RY0  (row0 *= e^{-i rz0/2}, row1 *= e^{+i rz0/2})
        float g00r =  cA*p0c, g00i = -cA*p0s;
        float g01r = -sA*p0c, g01i =  sA*p0s;
        float g10r =  sA*p0c, g10i =  sA*p0s;
        float g11r =  cA*p0c, g11i =  cA*p0s;
        // G2 = RY1 * G1 (real coefficients)
        float h00r = cB*g00r - sB*g10r, h00i = cB*g00i - sB*g10i;
        float h01r = cB*g01r - sB*g11r, h01i = cB*g01i - sB*g11i;
        float h10r = sB*g00r + cB*g10r, h10i = sB*g00i + cB*g10i;
        float h11r = sB*g01r + cB*g11r, h11i = sB*g01i + cB*g11i;
        // G3 = RZ1 * G2
        float f00r = h00r*p1c + h00i*p1s, f00i = h00i*p1c - h00r*p1s;
        float f01r = h01r*p1c + h01i*p1s, f01i = h01i*p1c - h01r*p1s;
        float f10r = h10r*p1c - h10i*p1s, f10i = h10i*p1c + h10r*p1s;
        float f11r = h11r*p1c - h11i*p1s, f11i = h11i*p1c + h11r*p1s;
        float DA = f00r*f00r + f00i*f00i - (f10r*f10r + f10i*f10i);
        float DB = f01r*f01r + f01i*f01i - (f11r*f11r + f11i*f11i);
        float Kr = (f00r*f01r + f00i*f01i) - (f10r*f11r + f10i*f11i);
        float Ki = (f00i*f01r - f00r*f01i) - (f10i*f11r - f10r*f11i);
        float* qc = (float*)((char*)ws + 16);
        qc[tid*4+0] = DA; qc[tid*4+1] = DB; qc[tid*4+2] = Kr; qc[tid*4+3] = Ki;
    }
}

// ---------- fused main ----------
template<int BF>
__device__ __forceinline__ void run_all(
    const void* hidden_, const void* W_in_, const void* b_in_,
    const void* W_out_, const void* b_out_, const void* gamma_, const void* beta_,
    void* out_, const float* qc,
    float* sWinT, float* sWout, float* sBout, float* sGamma, float* sBeta,
    float* sBin, float* sQC)
{
    const int tid = threadIdx.x;
    // stage params to LDS (fp32)
    for (int idx = tid; idx < HID*NQ; idx += TPB) {
        int j = idx / HID;
        int c = idx - j*HID;
        sWinT[c*NQ + j] = LDV<BF>(W_in_, idx);   // transposed [c][j]
        sWout[idx]      = LDV<BF>(W_out_, idx);  // [h][j] (input layout)
    }
    for (int idx = tid; idx < HID; idx += TPB) {
        sBout[idx]  = LDV<BF>(b_out_, idx);
        sGamma[idx] = LDV<BF>(gamma_, idx);
        sBeta[idx]  = LDV<BF>(beta_, idx);
    }
    if (tid < NQ)  sBin[tid] = LDV<BF>(b_in_, tid);
    if (tid < 4*NQ) sQC[tid] = qc[tid];
    __syncthreads();

    const int lane = tid & 63;
    const int wv   = tid >> 6;
    const int bbase = blockIdx.x * SPB + wv * 4;

    for (int s = 0; s < 4; ++s) {
        const int b = bbase + s;
        const int rowbase = b * HID;
        // ---- phase A: z_j = <hidden_b, W_in_j> ----
        float acc0=0,acc1=0,acc2=0,acc3=0,acc4=0,acc5=0,acc6=0,acc7=0;
        #pragma unroll
        for (int t = 0; t < 12; ++t) {
            int c = lane + (t << 6);
            float h = LDV<BF>(hidden_, rowbase + c);
            const float4* wp = (const float4*)(sWinT + c*NQ);
            float4 w0 = wp[0], w1 = wp[1];
            acc0 = fmaf(h, w0.x, acc0); acc1 = fmaf(h, w0.y, acc1);
            acc2 = fmaf(h, w0.z, acc2); acc3 = fmaf(h, w0.w, acc3);
            acc4 = fmaf(h, w1.x, acc4); acc5 = fmaf(h, w1.y, acc5);
            acc6 = fmaf(h, w1.z, acc6); acc7 = fmaf(h, w1.w, acc7);
        }
        float zz[NQ] = {acc0,acc1,acc2,acc3,acc4,acc5,acc6,acc7};
        #pragma unroll
        for (int d = 1; d < 64; d <<= 1) {
            #pragma unroll
            for (int j = 0; j < NQ; ++j) zz[j] += __shfl_xor(zz[j], d, 64);
        }
        // ---- circuit (factorized closed form), wave-uniform ----
        float sc[NQ], cc[NQ];
        #pragma unroll
        for (int j = 0; j < NQ; ++j) {
            float t_ = tanhf(zz[j] + sBin[j]);   // theta = pi * t_
            sc[j] = sinpif(t_);
            cc[j] = cospif(t_);
        }
        float meas[NQ];
        float PA = 1.f, PB = 1.f, PFr = 1.f, PFi = 0.f;
        #pragma unroll
        for (int j = 1; j < NQ; ++j) {
            float DA = sQC[4*j], DB = sQC[4*j+1], Kr = sQC[4*j+2], Ki = sQC[4*j+3];
            float ca = 0.5f*(DA+DB), da = 0.5f*(DA-DB);
            float u = da * cc[j];
            float v = fmaf(Kr, sc[j], ca);
            float MA = v + u, MB = v - u;
            meas[j] = fmaf(cc[0], u, v);
            PA *= MA; PB *= MB;
            float fr = Kr, fi = cc[j]*Ki;     // Fm_j
            float nr = PFr*fr - PFi*fi;
            float ni = PFr*fi + PFi*fr;
            PFr = nr; PFi = ni;
        }
        {
            float DA0 = sQC[0], DB0 = sQC[1], Kr0 = sQC[2], Ki0 = sQC[3];
            meas[0] = 0.5f*(1.f+cc[0])*DA0*PA + 0.5f*(1.f-cc[0])*DB0*PB
                    + sc[0]*(Kr0*PFr - Ki0*PFi);
        }
        // ---- phase C: y = meas @ W_out^T + b_out, LayerNorm, store ----
        float yv[12];
        float sum = 0.f, sumsq = 0.f;
        #pragma unroll
        for (int t = 0; t < 12; ++t) {
            int hc = lane + (t << 6);
            const float4* wp = (const float4*)(sWout + hc*NQ);
            float4 a0 = wp[0], a1 = wp[1];
            float y = sBout[hc];
            y = fmaf(meas[0], a0.x, y); y = fmaf(meas[1], a0.y, y);
            y = fmaf(meas[2], a0.z, y); y = fmaf(meas[3], a0.w, y);
            y = fmaf(meas[4], a1.x, y); y = fmaf(meas[5], a1.y, y);
            y = fmaf(meas[6], a1.z, y); y = fmaf(meas[7], a1.w, y);
            yv[t] = y;
            sum += y;
            sumsq = fmaf(y, y, sumsq);
        }
        #pragma unroll
        for (int d = 1; d < 64; d <<= 1) {
            sum   += __shfl_xor(sum,   d, 64);
            sumsq += __shfl_xor(sumsq, d, 64);
        }
        float mean = sum * (1.f/HID);
        float var  = sumsq * (1.f/HID) - mean*mean;
        float rstd = rsqrtf(var + 1e-5f);
        #pragma unroll
        for (int t = 0; t < 12; ++t) {
            int hc = lane + (t << 6);
            float o = (yv[t] - mean) * rstd * sGamma[hc] + sBeta[hc];
            STV<BF>(out_, rowbase + hc, o);
        }
    }
}

__global__ __launch_bounds__(TPB) void main_kernel(
    const void* hidden_, const void* W_in_, const void* b_in_,
    const void* W_out_, const void* b_out_, const void* gamma_, const void* beta_,
    void* out_, const void* ws_)
{
    __shared__ __align__(16) float sWinT[HID*NQ];
    __shared__ __align__(16) float sWout[HID*NQ];
    __shared__ float sBout[HID];
    __shared__ float sGamma[HID];
    __shared__ float sBeta[HID];
    __shared__ float sBin[NQ];
    __shared__ float sQC[4*NQ];
    const int flag = *(const int*)ws_;
    const float* qc = (const float*)((const char*)ws_ + 16);
    if (flag)
        run_all<1>(hidden_, W_in_, b_in_, W_out_, b_out_, gamma_, beta_, out_, qc,
                   sWinT, sWout, sBout, sGamma, sBeta, sBin, sQC);
    else
        run_all<0>(hidden_, W_in_, b_in_, W_out_, b_out_, gamma_, beta_, out_, qc,
                   sWinT, sWout, sBout, sGamma, sBeta, sBin, sQC);
}

extern "C" void kernel_launch(void* const* d_in, const int* in_sizes, int n_in,
                              void* d_out, int out_size, void* d_ws, size_t ws_size,
                              hipStream_t stream) {
    const void* hidden = d_in[0];
    const void* W_in   = d_in[1];
    const void* b_in   = d_in[2];
    const void* W_out  = d_in[3];
    const void* b_out  = d_in[4];
    const void* wry    = d_in[5];
    const void* wrz    = d_in[6];
    const void* gamma  = d_in[7];
    const void* beta   = d_in[8];
    setup_kernel<<<1, TPB, 0, stream>>>(hidden, wry, wrz, d_ws);
    main_kernel<<<NBLK, TPB, 0, stream>>>(hidden, W_in, b_in, W_out, b_out,
                                          gamma, beta, d_out, d_ws);
}